// Round 7
// baseline (39418.289 us; speedup 1.0000x reference)
//
#include <hip/hip_runtime.h>

// ---- geometry ----
#define PLANE28   784                  // 28*28
#define NPLANE28  (16*64*PLANE28)      // 802816  [16,64,28,28]
#define NPLANE56  (16*64*56*56)        // 3211264 [16,64,56,56]

// REROLL #1 (World-B hypothesis): fp32 pipeline, per-ic-subtotal reduction
// ordering (different draw vs r0/r1/r2/r3/r4). All materialized tensors fp32;
// elementwise membrane math fp32 with contraction off.

// =============== conv1 7x7 s2 p3 (20->64) + membrane ========================
__global__ __launch_bounds__(256) void conv1_k(
    const float* __restrict__ x,    // [16,8,20,112,112]
    const float* __restrict__ w1,   // [64,20,7,7]
    float* __restrict__ c_mem,      // [16,64,56,56]
    int t)
{
#pragma clang fp contract(off)
    int i = blockIdx.x * 256 + threadIdx.x;
    if (i >= NPLANE56) return;
    int xg = i % 56;
    int yg = (i / 56) % 56;
    int oc = (i / 3136) % 64;
    int n  = i / 200704;
    const float* xin = x + ((size_t)(n * 8 + t)) * 20 * 12544;
    const float* woc = w1 + (size_t)oc * 980;

    float acc = 0.f;
    for (int ic = 0; ic < 20; ++ic) {
        const float* xp = xin + ic * 12544;
        const float* wp = woc + ic * 49;
        float sub = 0.f;                       // per-channel subtotal
        for (int ky = 0; ky < 7; ++ky) {
            int iy = 2 * yg + ky - 3;
            if ((unsigned)iy >= 112u) continue;
            for (int kx = 0; kx < 7; ++kx) {
                int ix = 2 * xg + kx - 3;
                if ((unsigned)ix >= 112u) continue;
                sub = fmaf(xp[iy * 112 + ix], wp[ky * 7 + kx], sub);
            }
        }
        acc = acc + sub;
    }
    float m = c_mem[i] * 0.8f;
    m = m + acc;
    c_mem[i] = m;
}

// =============== avg_pool 3x3 s2 p1 on spikes(c_mem>0.5), /9 ================
__global__ __launch_bounds__(256) void pool1_k(const float* __restrict__ c_mem,
                                               float* __restrict__ cur) {
    int i = blockIdx.x * 256 + threadIdx.x;
    if (i >= NPLANE28) return;
    int xx = i % 28, yy = (i / 28) % 28;
    int p  = i / PLANE28;
    const float* src = c_mem + (size_t)p * 3136;
    float s = 0.f;
    for (int ky = 0; ky < 3; ++ky) {
        int iy = 2 * yy - 1 + ky;
        if ((unsigned)iy >= 56u) continue;
        for (int kx = 0; kx < 3; ++kx) {
            int ix = 2 * xx - 1 + kx;
            if ((unsigned)ix < 56u)
                s += (src[iy * 56 + ix] > 0.5f) ? 1.f : 0.f;
        }
    }
    cur[i] = s / 9.0f;
}

// =============== block conv A: 3x3 s1 p1, membrane, spike ===================
__global__ __launch_bounds__(256) void bconvA_k(
    const float* __restrict__ in,    // [16,64,28,28]
    const float* __restrict__ wb,    // [64,64,3,3]
    float* __restrict__ mem,
    float* __restrict__ sout)
{
#pragma clang fp contract(off)
    int i = blockIdx.x * 256 + threadIdx.x;
    if (i >= NPLANE28) return;
    int xx = i % 28;
    int yy = (i / 28) % 28;
    int oc = (i / 784) % 64;
    int n  = i / 50176;
    const float* base = in + (size_t)n * 64 * PLANE28;
    const float* woc = wb + (size_t)oc * 576;

    float acc = 0.f;
    for (int ic = 0; ic < 64; ++ic) {
        const float* xp = base + ic * PLANE28;
        const float* wp = woc + ic * 9;
        float sub = 0.f;                       // per-channel subtotal
        for (int ky = 0; ky < 3; ++ky) {
            int iy = yy + ky - 1;
            if ((unsigned)iy >= 28u) continue;
            for (int kx = 0; kx < 3; ++kx) {
                int ix = xx + kx - 1;
                if ((unsigned)ix < 28u)
                    sub = fmaf(xp[iy * 28 + ix], wp[ky * 3 + kx], sub);
            }
        }
        acc = acc + sub;
    }
    float m = mem[i] * 0.8f;
    m = m + acc;
    mem[i] = m;
    sout[i] = (m > 0.5f) ? 1.f : 0.f;
}

// =============== block conv B: + residual ===================================
__global__ __launch_bounds__(256) void bconvB_k(
    const float* __restrict__ in,    // s1 spikes
    const float* __restrict__ wb,
    float* __restrict__ mem,
    float* __restrict__ sout,
    const float* __restrict__ resid)
{
#pragma clang fp contract(off)
    int i = blockIdx.x * 256 + threadIdx.x;
    if (i >= NPLANE28) return;
    int xx = i % 28;
    int yy = (i / 28) % 28;
    int oc = (i / 784) % 64;
    int n  = i / 50176;
    const float* base = in + (size_t)n * 64 * PLANE28;
    const float* woc = wb + (size_t)oc * 576;

    float acc = 0.f;
    for (int ic = 0; ic < 64; ++ic) {
        const float* xp = base + ic * PLANE28;
        const float* wp = woc + ic * 9;
        float sub = 0.f;                       // per-channel subtotal
        for (int ky = 0; ky < 3; ++ky) {
            int iy = yy + ky - 1;
            if ((unsigned)iy >= 28u) continue;
            for (int kx = 0; kx < 3; ++kx) {
                int ix = xx + kx - 1;
                if ((unsigned)ix < 28u)
                    sub = fmaf(xp[iy * 28 + ix], wp[ky * 3 + kx], sub);
            }
        }
        acc = acc + sub;
    }
    float m = mem[i] * 0.8f;
    m = m + acc;
    m = m + resid[i];
    mem[i] = m;
    sout[i] = (m > 0.5f) ? 1.f : 0.f;
}

// =============== feat = avgpool7x7(concat s2 of blocks 0,2,4,6) =============
__global__ __launch_bounds__(256) void featpool_k(const float* __restrict__ s2all,
                                                  float* __restrict__ feat) {
    int i = blockIdx.x * 256 + threadIdx.x;   // 16*4096
    if (i >= 16 * 4096) return;
    int n = i >> 12;
    int f = i & 4095;
    int c = f >> 4;
    int py = (f >> 2) & 3, px = f & 3;
    int s = c >> 6, cc = c & 63;              // concat slice s -> block 2s
    const float* src = s2all + ((size_t)(2 * s) * 16 * 64 + n * 64 + cc) * PLANE28;
    float sum = 0.f;                          // <=49 integer: exact fp32
    for (int dy = 0; dy < 7; ++dy)
        for (int dx = 0; dx < 7; ++dx)
            sum += src[(py * 7 + dy) * 28 + px * 7 + dx];
    feat[i] = sum / 49.0f;
}

// =============== FC + membrane + spike + output accumulate ==================
__global__ __launch_bounds__(256) void fc_k(
    const float* __restrict__ feat, const float* __restrict__ w,
    const float* __restrict__ b, float* __restrict__ fc_mem,
    float* __restrict__ out) {
#pragma clang fp contract(off)
    int i = blockIdx.x * 256 + threadIdx.x;
    if (i >= 16 * 101) return;
    int n = i / 101, cls = i % 101;
    const float* f  = feat + (size_t)n * 4096;
    const float* wr = w + (size_t)cls * 4096;
    float acc = 0.f;
    for (int blk = 0; blk < 8; ++blk) {       // 8 x 512-term blocked chains
        float sub = 0.f;
        const float* fb = f + blk * 512;
        const float* wb = wr + blk * 512;
        for (int j = 0; j < 512; ++j)
            sub = fmaf(fb[j], wb[j], sub);
        acc = acc + sub;
    }
    float o = acc + b[cls];
    float m = fc_mem[i] * 0.8f;
    m = m + o;
    fc_mem[i] = m;
    if (m > 0.5f) out[i] += 0.125f;
}

extern "C" void kernel_launch(void* const* d_in, const int* in_sizes, int n_in,
                              void* d_out, int out_size, void* d_ws, size_t ws_size,
                              hipStream_t stream) {
    const float* x   = (const float*)d_in[0];
    const float* w1  = (const float*)d_in[1];
    const float* wb1 = (const float*)d_in[2];
    const float* wb2 = (const float*)d_in[3];
    const float* fcw = (const float*)d_in[4];
    const float* fcb = (const float*)d_in[5];
    float* out = (float*)d_out;

    // ---- workspace (all fp32): zeroed state first, then scratch
    float* fws    = (float*)d_ws;
    float* c_mem  = fws;                         // 3,211,264
    float* b1m    = c_mem + NPLANE56;            // 8*802,816
    float* b2m    = b1m + 8 * NPLANE28;          // 8*802,816
    float* fc_mem = b2m + 8 * NPLANE28;          // 1,616
    float* cur0   = fc_mem + 1616;               // 802,816
    float* feat   = cur0 + NPLANE28;             // 65,536
    float* s1     = feat + 16 * 4096;            // 802,816
    float* s2all  = s1 + NPLANE28;               // 8*802,816

    size_t zeroN = (size_t)NPLANE56 + 16 * NPLANE28 + 1616;
    hipMemsetAsync(c_mem, 0, zeroN * sizeof(float), stream);
    hipMemsetAsync(d_out, 0, 16 * 101 * sizeof(float), stream);

    for (int t = 0; t < 8; ++t) {
        conv1_k<<<NPLANE56 / 256, 256, 0, stream>>>(x, w1, c_mem, t);
        pool1_k<<<NPLANE28 / 256, 256, 0, stream>>>(c_mem, cur0);
        for (int i = 0; i < 8; ++i) {
            const float* wA = wb1 + (size_t)i * 36864;
            const float* wB = wb2 + (size_t)i * 36864;
            float* m1 = b1m + (size_t)i * NPLANE28;
            float* m2 = b2m + (size_t)i * NPLANE28;
            float* so = s2all + (size_t)i * NPLANE28;
            const float* bin = (i == 0) ? cur0 : s2all + (size_t)(i - 1) * NPLANE28;
            bconvA_k<<<NPLANE28 / 256, 256, 0, stream>>>(bin, wA, m1, s1);
            bconvB_k<<<NPLANE28 / 256, 256, 0, stream>>>(s1, wB, m2, so, bin);
        }
        featpool_k<<<16 * 4096 / 256, 256, 0, stream>>>(s2all, feat);
        fc_k<<<(16 * 101 + 255) / 256, 256, 0, stream>>>(feat, fcw, fcb, fc_mem, out);
    }
}

// Round 8
// 10167.966 us; speedup vs baseline: 3.8767x; 3.8767x over previous
//
#include <hip/hip_runtime.h>

// ---- geometry ----
#define PLANE28   784                  // 28*28
#define NPLANE28  (16*64*PLANE28)      // 802816  [16,64,28,28]
#define NPLANE56  (16*64*56*56)        // 3211264 [16,64,56,56]
#define C1_TILE   (117*37)             // 4329

// FROZEN SEMANTICS (validated round 7, absmax=0):
//  - conv reductions: per-ic subtotal. sub = fmaf chain over (ky outer, kx inner),
//    OOB skipped (== zero-padded fmaf no-op); acc = acc + sub in ic order.
//  - membrane: m = mem*0.8f; m = m + conv; [m = m + resid;]  (contract OFF)
//  - fc: 8 x 512-term sequential fmaf chains, acc = acc + sub; o = acc + b.
//  - pool sums are exact small integers (order-free), divided by 9.0f / 49.0f.

// ---------------- weight transposes (once per launch) -----------------------
// conv1_w [64oc][20ic][7ky][7kx] -> w1t [20ic][7ky][7kx][64oc]
__global__ __launch_bounds__(256) void transpose_w1(const float* __restrict__ w,
                                                    float* __restrict__ wt) {
    int i = blockIdx.x * 256 + threadIdx.x;
    if (i >= 64 * 20 * 49) return;
    int oc = i / 980;
    int r  = i % 980;
    int ic = r / 49;
    int ky = (r % 49) / 7;
    int kx = r % 7;
    wt[((ic * 7 + ky) * 7 + kx) * 64 + oc] = w[i];
}

// blocks_w [8][64oc][64ic][3ky][3kx] -> wt [8][64ic][3ky][3kx][64oc]
__global__ __launch_bounds__(256) void transpose_wb(const float* __restrict__ w,
                                                    float* __restrict__ wt) {
    int i = blockIdx.x * 256 + threadIdx.x;
    if (i >= 8 * 64 * 64 * 9) return;
    int l  = i / 36864;
    int r  = i % 36864;
    int oc = r / 576;
    int r2 = r % 576;
    int ic = r2 / 9;
    int ky = (r2 % 9) / 3;
    int kx = r2 % 3;
    wt[l * 36864 + ((ic * 3 + ky) * 3 + kx) * 64 + oc] = w[i];
}

// ---------------- conv1 7x7 s2 p3 (20->64) + membrane, tiled ----------------
// grid (4 xtiles, 8 ocg, 16 n), block 256. thread: 8 ocs x 4 rows.
__global__ __launch_bounds__(256) void conv1_t(
    const float* __restrict__ x,    // [16,8,20,112,112]
    const float* __restrict__ wt,   // [20][7][7][64]
    float* __restrict__ c_mem,      // [16,64,56,56]
    int t)
{
    __shared__ float tile[C1_TILE];
    const int tid = threadIdx.x;
    const int bx  = blockIdx.x;          // 0..3
    const int oc0 = blockIdx.y * 8;
    const int n   = blockIdx.z;
    const int tx  = tid & 15;
    const int tyq = tid >> 4;            // 0..15, compute active tyq<14
    const float* xin = x + ((size_t)(n * 8 + t)) * 20 * 12544;
    const int cbase = 32 * bx - 3;

    float acc[8][4];
#pragma unroll
    for (int o = 0; o < 8; ++o)
#pragma unroll
        for (int d = 0; d < 4; ++d) acc[o][d] = 0.f;

    // stage ic=0
#pragma unroll
    for (int k = 0; k < 17; ++k) {
        int idx = tid + k * 256;
        if (idx < C1_TILE) {
            int r = idx / 37, c = idx - r * 37;
            int ri = r - 3, ci = cbase + c;
            float v = 0.f;
            if ((unsigned)ri < 112u && (unsigned)ci < 112u) v = xin[ri * 112 + ci];
            tile[idx] = v;
        }
    }

    for (int ic = 0; ic < 20; ++ic) {
        __syncthreads();
        float pre[17];
        if (ic + 1 < 20) {
            const float* src = xin + (ic + 1) * 12544;
#pragma unroll
            for (int k = 0; k < 17; ++k) {
                int idx = tid + k * 256;
                float v = 0.f;
                if (idx < C1_TILE) {
                    int r = idx / 37, c = idx - r * 37;
                    int ri = r - 3, ci = cbase + c;
                    if ((unsigned)ri < 112u && (unsigned)ci < 112u) v = src[ri * 112 + ci];
                }
                pre[k] = v;
            }
        }
        if (tyq < 14) {
            float sub[8][4];
#pragma unroll
            for (int o = 0; o < 8; ++o)
#pragma unroll
                for (int d = 0; d < 4; ++d) sub[o][d] = 0.f;
            const float* wic = wt + ic * (49 * 64) + oc0;
#pragma unroll
            for (int ky = 0; ky < 7; ++ky) {     // ky OUTER (frozen order)
#pragma unroll
                for (int kx = 0; kx < 7; ++kx) { // kx INNER
                    const float* wp = wic + (ky * 7 + kx) * 64;  // uniform -> s_load
                    float v[4];
#pragma unroll
                    for (int d = 0; d < 4; ++d)
                        v[d] = tile[(8 * tyq + 2 * d + ky) * 37 + 2 * tx + kx];
#pragma unroll
                    for (int o = 0; o < 8; ++o) {
                        const float wv = wp[o];
#pragma unroll
                        for (int d = 0; d < 4; ++d)
                            sub[o][d] = fmaf(v[d], wv, sub[o][d]);
                    }
                }
            }
#pragma unroll
            for (int o = 0; o < 8; ++o)
#pragma unroll
                for (int d = 0; d < 4; ++d) acc[o][d] = acc[o][d] + sub[o][d];
        }
        __syncthreads();
        if (ic + 1 < 20) {
#pragma unroll
            for (int k = 0; k < 17; ++k) {
                int idx = tid + k * 256;
                if (idx < C1_TILE) tile[idx] = pre[k];
            }
        }
    }

    const int xg = 16 * bx + tx;
    if (tyq < 14 && xg < 56) {
#pragma clang fp contract(off)
#pragma unroll
        for (int o = 0; o < 8; ++o) {
#pragma unroll
            for (int d = 0; d < 4; ++d) {
                const int yg = 4 * tyq + d;
                size_t idx = (((size_t)n * 64 + oc0 + o) * 56 + yg) * 56 + xg;
                float m = c_mem[idx] * 0.8f;
                m = m + acc[o][d];
                c_mem[idx] = m;
            }
        }
    }
}

// ---------------- avg_pool 3x3 s2 p1 on spikes(c_mem>0.5), /9 ---------------
__global__ __launch_bounds__(256) void pool1_k(const float* __restrict__ c_mem,
                                               float* __restrict__ cur) {
    int i = blockIdx.x * 256 + threadIdx.x;
    if (i >= NPLANE28) return;
    int xx = i % 28, yy = (i / 28) % 28;
    int p  = i / PLANE28;
    const float* src = c_mem + (size_t)p * 3136;
    float s = 0.f;
    for (int ky = 0; ky < 3; ++ky) {
        int iy = 2 * yy - 1 + ky;
        if ((unsigned)iy >= 56u) continue;
        for (int kx = 0; kx < 3; ++kx) {
            int ix = 2 * xx - 1 + kx;
            if ((unsigned)ix < 56u)
                s += (src[iy * 56 + ix] > 0.5f) ? 1.f : 0.f;
        }
    }
    cur[i] = s / 9.0f;
}

// ---------------- block conv 3x3 s1 p1 (64->64), tiled ----------------------
// grid (2 yhalves, 16 ocg, 16 n), block 256 (196 active). thread: 4 ocs x 2 rows.
template <bool HASRES>
__global__ __launch_bounds__(256) void bconv_t(
    const float* __restrict__ in,     // [16,64,28,28]
    const float* __restrict__ wt,     // [64ic][3ky][3kx][64oc] (this layer)
    float* __restrict__ mem,
    float* __restrict__ sout,
    const float* __restrict__ resid)
{
    __shared__ float tile[480];       // 16 rows x 30 cols, zero-padded
    const int tid = threadIdx.x;
    const int yh  = blockIdx.x;       // 0..1
    const int oc0 = blockIdx.y * 4;
    const int n   = blockIdx.z;
    const int xx  = tid % 28;
    const int tyq = tid / 28;         // 0..9, active <7
    const bool act = tid < 196;
    const int row0 = yh * 14 - 1;     // input row of tile row 0
    const float* base = in + (size_t)n * 64 * PLANE28;

    float acc[4][2];
#pragma unroll
    for (int o = 0; o < 4; ++o) { acc[o][0] = 0.f; acc[o][1] = 0.f; }

    // stage ic=0
#pragma unroll
    for (int k = 0; k < 2; ++k) {
        int idx = tid + k * 256;
        if (idx < 480) {
            int r = idx / 30, c = idx - r * 30;
            int ri = row0 + r, ci = c - 1;
            float v = 0.f;
            if ((unsigned)ri < 28u && (unsigned)ci < 28u) v = base[ri * 28 + ci];
            tile[idx] = v;
        }
    }

    for (int ic = 0; ic < 64; ++ic) {
        __syncthreads();
        float pre[2] = {0.f, 0.f};
        if (ic + 1 < 64) {
            const float* src = base + (ic + 1) * PLANE28;
#pragma unroll
            for (int k = 0; k < 2; ++k) {
                int idx = tid + k * 256;
                if (idx < 480) {
                    int r = idx / 30, c = idx - r * 30;
                    int ri = row0 + r, ci = c - 1;
                    if ((unsigned)ri < 28u && (unsigned)ci < 28u) pre[k] = src[ri * 28 + ci];
                }
            }
        }
        if (act) {
            float sub[4][2];
#pragma unroll
            for (int o = 0; o < 4; ++o) { sub[o][0] = 0.f; sub[o][1] = 0.f; }
            const float* wic = wt + ic * (9 * 64) + oc0;
#pragma unroll
            for (int ky = 0; ky < 3; ++ky) {     // ky OUTER (frozen order)
#pragma unroll
                for (int kx = 0; kx < 3; ++kx) { // kx INNER
                    const float* wp = wic + (ky * 3 + kx) * 64;  // uniform -> s_load
                    const float v0 = tile[(2 * tyq + 0 + ky) * 30 + xx + kx];
                    const float v1 = tile[(2 * tyq + 1 + ky) * 30 + xx + kx];
#pragma unroll
                    for (int o = 0; o < 4; ++o) {
                        const float wv = wp[o];
                        sub[o][0] = fmaf(v0, wv, sub[o][0]);
                        sub[o][1] = fmaf(v1, wv, sub[o][1]);
                    }
                }
            }
#pragma unroll
            for (int o = 0; o < 4; ++o) {
                acc[o][0] = acc[o][0] + sub[o][0];
                acc[o][1] = acc[o][1] + sub[o][1];
            }
        }
        __syncthreads();
        if (ic + 1 < 64) {
#pragma unroll
            for (int k = 0; k < 2; ++k) {
                int idx = tid + k * 256;
                if (idx < 480) tile[idx] = pre[k];
            }
        }
    }

    if (act) {
#pragma clang fp contract(off)
#pragma unroll
        for (int o = 0; o < 4; ++o) {
#pragma unroll
            for (int d = 0; d < 2; ++d) {
                int yg = yh * 14 + 2 * tyq + d;
                size_t idx = (((size_t)n * 64 + oc0 + o) * 28 + yg) * 28 + xx;
                float m = mem[idx] * 0.8f;
                m = m + acc[o][d];
                if (HASRES) m = m + resid[idx];
                mem[idx] = m;
                sout[idx] = (m > 0.5f) ? 1.f : 0.f;
            }
        }
    }
}

// ---------------- feat = avgpool7x7(concat s2 of blocks 0,2,4,6) ------------
__global__ __launch_bounds__(256) void featpool_k(const float* __restrict__ s2all,
                                                  float* __restrict__ feat) {
    int i = blockIdx.x * 256 + threadIdx.x;
    if (i >= 16 * 4096) return;
    int n = i >> 12;
    int f = i & 4095;
    int c = f >> 4;
    int py = (f >> 2) & 3, px = f & 3;
    int s = c >> 6, cc = c & 63;
    const float* src = s2all + ((size_t)(2 * s) * 16 * 64 + n * 64 + cc) * PLANE28;
    float sum = 0.f;
    for (int dy = 0; dy < 7; ++dy)
        for (int dx = 0; dx < 7; ++dx)
            sum += src[(py * 7 + dy) * 28 + px * 7 + dx];
    feat[i] = sum / 49.0f;
}

// ---------------- FC + membrane + spike + output accumulate -----------------
__global__ __launch_bounds__(256) void fc_k(
    const float* __restrict__ feat, const float* __restrict__ w,
    const float* __restrict__ b, float* __restrict__ fc_mem,
    float* __restrict__ out) {
#pragma clang fp contract(off)
    int i = blockIdx.x * 256 + threadIdx.x;
    if (i >= 16 * 101) return;
    int n = i / 101, cls = i % 101;
    const float* f  = feat + (size_t)n * 4096;
    const float* wr = w + (size_t)cls * 4096;
    float acc = 0.f;
    for (int blk = 0; blk < 8; ++blk) {
        float sub = 0.f;
        const float* fb = f + blk * 512;
        const float* wb = wr + blk * 512;
        for (int j = 0; j < 512; ++j)
            sub = fmaf(fb[j], wb[j], sub);
        acc = acc + sub;
    }
    float o = acc + b[cls];
    float m = fc_mem[i] * 0.8f;
    m = m + o;
    fc_mem[i] = m;
    if (m > 0.5f) out[i] += 0.125f;
}

extern "C" void kernel_launch(void* const* d_in, const int* in_sizes, int n_in,
                              void* d_out, int out_size, void* d_ws, size_t ws_size,
                              hipStream_t stream) {
    const float* x   = (const float*)d_in[0];
    const float* w1  = (const float*)d_in[1];
    const float* wb1 = (const float*)d_in[2];
    const float* wb2 = (const float*)d_in[3];
    const float* fcw = (const float*)d_in[4];
    const float* fcb = (const float*)d_in[5];
    float* out = (float*)d_out;

    // ---- workspace (all fp32): zeroed state first, then scratch
    float* fws    = (float*)d_ws;
    float* c_mem  = fws;                         // 3,211,264
    float* b1m    = c_mem + NPLANE56;            // 8*802,816
    float* b2m    = b1m + 8 * NPLANE28;          // 8*802,816
    float* fc_mem = b2m + 8 * NPLANE28;          // 1,616
    float* cur0   = fc_mem + 1616;               // 802,816
    float* feat   = cur0 + NPLANE28;             // 65,536
    float* s1     = feat + 16 * 4096;            // 802,816
    float* s2all  = s1 + NPLANE28;               // 8*802,816
    float* w1t    = s2all + 8 * NPLANE28;        // 62,720
    float* wb1t   = w1t + 62720;                 // 294,912
    float* wb2t   = wb1t + 294912;               // 294,912

    size_t zeroN = (size_t)NPLANE56 + 16 * NPLANE28 + 1616;
    hipMemsetAsync(c_mem, 0, zeroN * sizeof(float), stream);
    hipMemsetAsync(d_out, 0, 16 * 101 * sizeof(float), stream);

    transpose_w1<<<(62720 + 255) / 256, 256, 0, stream>>>(w1, w1t);
    transpose_wb<<<(294912 + 255) / 256, 256, 0, stream>>>(wb1, wb1t);
    transpose_wb<<<(294912 + 255) / 256, 256, 0, stream>>>(wb2, wb2t);

    for (int t = 0; t < 8; ++t) {
        conv1_t<<<dim3(4, 8, 16), 256, 0, stream>>>(x, w1t, c_mem, t);
        pool1_k<<<NPLANE28 / 256, 256, 0, stream>>>(c_mem, cur0);
        for (int i = 0; i < 8; ++i) {
            const float* wA = wb1t + (size_t)i * 36864;
            const float* wB = wb2t + (size_t)i * 36864;
            float* m1 = b1m + (size_t)i * NPLANE28;
            float* m2 = b2m + (size_t)i * NPLANE28;
            float* so = s2all + (size_t)i * NPLANE28;
            const float* bin = (i == 0) ? cur0 : s2all + (size_t)(i - 1) * NPLANE28;
            bconv_t<false><<<dim3(2, 16, 16), 256, 0, stream>>>(bin, wA, m1, s1, nullptr);
            bconv_t<true><<<dim3(2, 16, 16), 256, 0, stream>>>(s1, wB, m2, so, bin);
        }
        featpool_k<<<16 * 4096 / 256, 256, 0, stream>>>(s2all, feat);
        fc_k<<<(16 * 101 + 255) / 256, 256, 0, stream>>>(feat, fcw, fcb, fc_mem, out);
    }
}

// Round 9
// 9677.482 us; speedup vs baseline: 4.0732x; 1.0507x over previous
//
#include <hip/hip_runtime.h>

// ---- geometry ----
#define PLANE28   784                  // 28*28
#define NPLANE28  (16*64*PLANE28)      // 802816  [16,64,28,28]
#define NPLANE56  (16*64*56*56)        // 3211264 [16,64,56,56]
#define C1_TILE   (117*37)             // 4329

// FROZEN SEMANTICS (validated rounds 7/8, absmax=0):
//  - conv reductions: per-ic subtotal. sub = fmaf chain over (ky outer, kx inner),
//    OOB skipped (== zero-padded fmaf no-op); acc = acc + sub in ic order.
//  - membrane: m = mem*0.8f; m = m + conv; [m = m + resid;]  (contract OFF)
//  - fc: 8 x 512-term sequential fmaf chains, acc = acc + sub; o = acc + b.
//  - pool sums are exact small integers (order-free), divided by 9.0f / 49.0f.

// ---------------- weight transposes (once per launch) -----------------------
// conv1_w [64oc][20ic][7ky][7kx] -> w1t [20ic][7ky][7kx][64oc]
__global__ __launch_bounds__(256) void transpose_w1(const float* __restrict__ w,
                                                    float* __restrict__ wt) {
    int i = blockIdx.x * 256 + threadIdx.x;
    if (i >= 64 * 20 * 49) return;
    int oc = i / 980;
    int r  = i % 980;
    int ic = r / 49;
    int ky = (r % 49) / 7;
    int kx = r % 7;
    wt[((ic * 7 + ky) * 7 + kx) * 64 + oc] = w[i];
}

// blocks_w [8][64oc][64ic][3ky][3kx] -> wt [8][64ic][3ky][3kx][64oc]
__global__ __launch_bounds__(256) void transpose_wb(const float* __restrict__ w,
                                                    float* __restrict__ wt) {
    int i = blockIdx.x * 256 + threadIdx.x;
    if (i >= 8 * 64 * 64 * 9) return;
    int l  = i / 36864;
    int r  = i % 36864;
    int oc = r / 576;
    int r2 = r % 576;
    int ic = r2 / 9;
    int ky = (r2 % 9) / 3;
    int kx = r2 % 3;
    wt[l * 36864 + ((ic * 3 + ky) * 3 + kx) * 64 + oc] = w[i];
}

// ---------------- conv1 7x7 s2 p3 (20->64) + membrane, tiled ----------------
// (unchanged from round 8 — passed)
__global__ __launch_bounds__(256) void conv1_t(
    const float* __restrict__ x,    // [16,8,20,112,112]
    const float* __restrict__ wt,   // [20][7][7][64]
    float* __restrict__ c_mem,      // [16,64,56,56]
    int t)
{
    __shared__ float tile[C1_TILE];
    const int tid = threadIdx.x;
    const int bx  = blockIdx.x;          // 0..3
    const int oc0 = blockIdx.y * 8;
    const int n   = blockIdx.z;
    const int tx  = tid & 15;
    const int tyq = tid >> 4;            // 0..15, compute active tyq<14
    const float* xin = x + ((size_t)(n * 8 + t)) * 20 * 12544;
    const int cbase = 32 * bx - 3;

    float acc[8][4];
#pragma unroll
    for (int o = 0; o < 8; ++o)
#pragma unroll
        for (int d = 0; d < 4; ++d) acc[o][d] = 0.f;

#pragma unroll
    for (int k = 0; k < 17; ++k) {
        int idx = tid + k * 256;
        if (idx < C1_TILE) {
            int r = idx / 37, c = idx - r * 37;
            int ri = r - 3, ci = cbase + c;
            float v = 0.f;
            if ((unsigned)ri < 112u && (unsigned)ci < 112u) v = xin[ri * 112 + ci];
            tile[idx] = v;
        }
    }

    for (int ic = 0; ic < 20; ++ic) {
        __syncthreads();
        float pre[17];
        if (ic + 1 < 20) {
            const float* src = xin + (ic + 1) * 12544;
#pragma unroll
            for (int k = 0; k < 17; ++k) {
                int idx = tid + k * 256;
                float v = 0.f;
                if (idx < C1_TILE) {
                    int r = idx / 37, c = idx - r * 37;
                    int ri = r - 3, ci = cbase + c;
                    if ((unsigned)ri < 112u && (unsigned)ci < 112u) v = src[ri * 112 + ci];
                }
                pre[k] = v;
            }
        }
        if (tyq < 14) {
            float sub[8][4];
#pragma unroll
            for (int o = 0; o < 8; ++o)
#pragma unroll
                for (int d = 0; d < 4; ++d) sub[o][d] = 0.f;
            const float* wic = wt + ic * (49 * 64) + oc0;
#pragma unroll
            for (int ky = 0; ky < 7; ++ky) {     // ky OUTER (frozen order)
#pragma unroll
                for (int kx = 0; kx < 7; ++kx) { // kx INNER
                    const float* wp = wic + (ky * 7 + kx) * 64;
                    float v[4];
#pragma unroll
                    for (int d = 0; d < 4; ++d)
                        v[d] = tile[(8 * tyq + 2 * d + ky) * 37 + 2 * tx + kx];
#pragma unroll
                    for (int o = 0; o < 8; ++o) {
                        const float wv = wp[o];
#pragma unroll
                        for (int d = 0; d < 4; ++d)
                            sub[o][d] = fmaf(v[d], wv, sub[o][d]);
                    }
                }
            }
#pragma unroll
            for (int o = 0; o < 8; ++o)
#pragma unroll
                for (int d = 0; d < 4; ++d) acc[o][d] = acc[o][d] + sub[o][d];
        }
        __syncthreads();
        if (ic + 1 < 20) {
#pragma unroll
            for (int k = 0; k < 17; ++k) {
                int idx = tid + k * 256;
                if (idx < C1_TILE) tile[idx] = pre[k];
            }
        }
    }

    const int xg = 16 * bx + tx;
    if (tyq < 14 && xg < 56) {
#pragma clang fp contract(off)
#pragma unroll
        for (int o = 0; o < 8; ++o) {
#pragma unroll
            for (int d = 0; d < 4; ++d) {
                const int yg = 4 * tyq + d;
                size_t idx = (((size_t)n * 64 + oc0 + o) * 56 + yg) * 56 + xg;
                float m = c_mem[idx] * 0.8f;
                m = m + acc[o][d];
                c_mem[idx] = m;
            }
        }
    }
}

// ---------------- avg_pool 3x3 s2 p1 on spikes(c_mem>0.5), /9 ---------------
__global__ __launch_bounds__(256) void pool1_k(const float* __restrict__ c_mem,
                                               float* __restrict__ cur) {
    int i = blockIdx.x * 256 + threadIdx.x;
    if (i >= NPLANE28) return;
    int xx = i % 28, yy = (i / 28) % 28;
    int p  = i / PLANE28;
    const float* src = c_mem + (size_t)p * 3136;
    float s = 0.f;
    for (int ky = 0; ky < 3; ++ky) {
        int iy = 2 * yy - 1 + ky;
        if ((unsigned)iy >= 56u) continue;
        for (int kx = 0; kx < 3; ++kx) {
            int ix = 2 * xx - 1 + kx;
            if ((unsigned)ix < 56u)
                s += (src[iy * 56 + ix] > 0.5f) ? 1.f : 0.f;
        }
    }
    cur[i] = s / 9.0f;
}

// ---------------- block conv 3x3 s1 p1 (64->64), v2 -------------------------
// grid (4 yq, 8 ocg, 16 n) = 512 blocks; block 256 (196 active).
// thread = 1 pixel x 8 ocs. One barrier per ic phase (double-buffered LDS).
template <bool HASRES>
__global__ __launch_bounds__(256) void bconv_v2(
    const float* __restrict__ in,     // [16,64,28,28]
    const float* __restrict__ wt,     // [64ic][3ky][3kx][64oc] (this layer)
    float* __restrict__ mem,
    float* __restrict__ sout,
    const float* __restrict__ resid)
{
    __shared__ float tile[2][270];    // 9 rows x 30 cols, zero-padded halo
    const int tid = threadIdx.x;
    const int yq  = blockIdx.x;       // 0..3 -> output rows 7yq..7yq+6
    const int oc0 = blockIdx.y * 8;
    const int n   = blockIdx.z;
    const int xx  = tid % 28;
    const int rl  = tid / 28;         // 0..9, active rl<7
    const bool act = tid < 196;
    const int row0 = yq * 7 - 1;      // input row of tile row 0
    const float* base = in + (size_t)n * 64 * PLANE28;

    // stage coords (computed once)
    int sr0 = tid / 30, sc0 = tid - sr0 * 30;
    int sri0 = row0 + sr0, sci0 = sc0 - 1;
    const bool sv0 = (tid < 270) && ((unsigned)sri0 < 28u) && ((unsigned)sci0 < 28u);
    int idx2 = tid + 256;
    int sr1 = idx2 / 30, sc1 = idx2 - sr1 * 30;
    int sri1 = row0 + sr1, sci1 = sc1 - 1;
    const bool sv1 = (tid < 14) && ((unsigned)sri1 < 28u) && ((unsigned)sci1 < 28u);

    float acc[8];
#pragma unroll
    for (int o = 0; o < 8; ++o) acc[o] = 0.f;

    // stage ic=0 into buf 0
    if (tid < 270) tile[0][tid] = sv0 ? base[sri0 * 28 + sci0] : 0.f;
    if (tid < 14)  tile[0][idx2] = sv1 ? base[sri1 * 28 + sci1] : 0.f;
    __syncthreads();

    int cur = 0;
    for (int ic = 0; ic < 64; ++ic) {
        // prefetch next channel into registers (issue early)
        float p0 = 0.f, p1 = 0.f;
        if (ic + 1 < 64) {
            const float* src = base + (ic + 1) * PLANE28;
            if (sv0) p0 = src[sri0 * 28 + sci0];
            if (sv1) p1 = src[sri1 * 28 + sci1];
        }
        if (act) {
            float sub[8];
#pragma unroll
            for (int o = 0; o < 8; ++o) sub[o] = 0.f;
            const float* wic = wt + ic * 576 + oc0;
#pragma unroll
            for (int ky = 0; ky < 3; ++ky) {     // ky OUTER (frozen order)
#pragma unroll
                for (int kx = 0; kx < 3; ++kx) { // kx INNER
                    const float v = tile[cur][(rl + ky) * 30 + xx + kx];
                    const float* wp = wic + (ky * 3 + kx) * 64;  // uniform -> s_load
#pragma unroll
                    for (int o = 0; o < 8; ++o)
                        sub[o] = fmaf(v, wp[o], sub[o]);
                }
            }
#pragma unroll
            for (int o = 0; o < 8; ++o) acc[o] = acc[o] + sub[o];
        }
        if (ic + 1 < 64) {
            if (tid < 270) tile[cur ^ 1][tid] = p0;
            if (tid < 14)  tile[cur ^ 1][idx2] = p1;
        }
        __syncthreads();
        cur ^= 1;
    }

    if (act) {
#pragma clang fp contract(off)
        const int yg = yq * 7 + rl;
#pragma unroll
        for (int o = 0; o < 8; ++o) {
            size_t idx = (((size_t)n * 64 + oc0 + o) * 28 + yg) * 28 + xx;
            float m = mem[idx] * 0.8f;
            m = m + acc[o];
            if (HASRES) m = m + resid[idx];
            mem[idx] = m;
            sout[idx] = (m > 0.5f) ? 1.f : 0.f;
        }
    }
}

// ---------------- feat = avgpool7x7(concat s2 of blocks 0,2,4,6) ------------
__global__ __launch_bounds__(256) void featpool_k(const float* __restrict__ s2all,
                                                  float* __restrict__ feat) {
    int i = blockIdx.x * 256 + threadIdx.x;
    if (i >= 16 * 4096) return;
    int n = i >> 12;
    int f = i & 4095;
    int c = f >> 4;
    int py = (f >> 2) & 3, px = f & 3;
    int s = c >> 6, cc = c & 63;
    const float* src = s2all + ((size_t)(2 * s) * 16 * 64 + n * 64 + cc) * PLANE28;
    float sum = 0.f;
    for (int dy = 0; dy < 7; ++dy)
        for (int dx = 0; dx < 7; ++dx)
            sum += src[(py * 7 + dy) * 28 + px * 7 + dx];
    feat[i] = sum / 49.0f;
}

// ---------------- FC + membrane + spike + output accumulate -----------------
__global__ __launch_bounds__(256) void fc_k(
    const float* __restrict__ feat, const float* __restrict__ w,
    const float* __restrict__ b, float* __restrict__ fc_mem,
    float* __restrict__ out) {
#pragma clang fp contract(off)
    int i = blockIdx.x * 256 + threadIdx.x;
    if (i >= 16 * 101) return;
    int n = i / 101, cls = i % 101;
    const float* f  = feat + (size_t)n * 4096;
    const float* wr = w + (size_t)cls * 4096;
    float acc = 0.f;
    for (int blk = 0; blk < 8; ++blk) {
        float sub = 0.f;
        const float* fb = f + blk * 512;
        const float* wb = wr + blk * 512;
        for (int j = 0; j < 512; ++j)
            sub = fmaf(fb[j], wb[j], sub);
        acc = acc + sub;
    }
    float o = acc + b[cls];
    float m = fc_mem[i] * 0.8f;
    m = m + o;
    fc_mem[i] = m;
    if (m > 0.5f) out[i] += 0.125f;
}

extern "C" void kernel_launch(void* const* d_in, const int* in_sizes, int n_in,
                              void* d_out, int out_size, void* d_ws, size_t ws_size,
                              hipStream_t stream) {
    const float* x   = (const float*)d_in[0];
    const float* w1  = (const float*)d_in[1];
    const float* wb1 = (const float*)d_in[2];
    const float* wb2 = (const float*)d_in[3];
    const float* fcw = (const float*)d_in[4];
    const float* fcb = (const float*)d_in[5];
    float* out = (float*)d_out;

    // ---- workspace (all fp32): zeroed state first, then scratch
    float* fws    = (float*)d_ws;
    float* c_mem  = fws;                         // 3,211,264
    float* b1m    = c_mem + NPLANE56;            // 8*802,816
    float* b2m    = b1m + 8 * NPLANE28;          // 8*802,816
    float* fc_mem = b2m + 8 * NPLANE28;          // 1,616
    float* cur0   = fc_mem + 1616;               // 802,816
    float* feat   = cur0 + NPLANE28;             // 65,536
    float* s1     = feat + 16 * 4096;            // 802,816
    float* s2all  = s1 + NPLANE28;               // 8*802,816
    float* w1t    = s2all + 8 * NPLANE28;        // 62,720
    float* wb1t   = w1t + 62720;                 // 294,912
    float* wb2t   = wb1t + 294912;               // 294,912

    size_t zeroN = (size_t)NPLANE56 + 16 * NPLANE28 + 1616;
    hipMemsetAsync(c_mem, 0, zeroN * sizeof(float), stream);
    hipMemsetAsync(d_out, 0, 16 * 101 * sizeof(float), stream);

    transpose_w1<<<(62720 + 255) / 256, 256, 0, stream>>>(w1, w1t);
    transpose_wb<<<(294912 + 255) / 256, 256, 0, stream>>>(wb1, wb1t);
    transpose_wb<<<(294912 + 255) / 256, 256, 0, stream>>>(wb2, wb2t);

    for (int t = 0; t < 8; ++t) {
        conv1_t<<<dim3(4, 8, 16), 256, 0, stream>>>(x, w1t, c_mem, t);
        pool1_k<<<NPLANE28 / 256, 256, 0, stream>>>(c_mem, cur0);
        for (int i = 0; i < 8; ++i) {
            const float* wA = wb1t + (size_t)i * 36864;
            const float* wB = wb2t + (size_t)i * 36864;
            float* m1 = b1m + (size_t)i * NPLANE28;
            float* m2 = b2m + (size_t)i * NPLANE28;
            float* so = s2all + (size_t)i * NPLANE28;
            const float* bin = (i == 0) ? cur0 : s2all + (size_t)(i - 1) * NPLANE28;
            bconv_v2<false><<<dim3(4, 8, 16), 256, 0, stream>>>(bin, wA, m1, s1, nullptr);
            bconv_v2<true><<<dim3(4, 8, 16), 256, 0, stream>>>(s1, wB, m2, so, bin);
        }
        featpool_k<<<16 * 4096 / 256, 256, 0, stream>>>(s2all, feat);
        fc_k<<<(16 * 101 + 255) / 256, 256, 0, stream>>>(feat, fcw, fcb, fc_mem, out);
    }
}

// Round 10
// 6612.978 us; speedup vs baseline: 5.9607x; 1.4634x over previous
//
#include <hip/hip_runtime.h>

// ---- geometry ----
#define PLANE28   784                  // 28*28
#define NPLANE28  (16*64*PLANE28)      // 802816  [16,64,28,28]
#define NPLANE56  (16*64*56*56)        // 3211264 [16,64,56,56]
#define C1T_ROWS  61
#define C1T       (C1T_ROWS*37)        // 2257

// FROZEN SEMANTICS (validated rounds 7/8/9, absmax=0):
//  - conv reductions: per-ic subtotal. sub = fmaf chain over (ky outer, kx inner),
//    OOB skipped (== zero-padded fmaf no-op); acc = acc + sub in ic order.
//  - membrane: m = mem*0.8f; m = m + conv; [m = m + resid;]  (contract OFF)
//  - fc: 8 x 512-term sequential fmaf chains, acc = acc + sub (in order); o = acc + b.
//  - pool sums are exact small integers (order-free), divided by 9.0f / 49.0f.

// ---------------- weight transposes (once per launch) -----------------------
__global__ __launch_bounds__(256) void transpose_w1(const float* __restrict__ w,
                                                    float* __restrict__ wt) {
    int i = blockIdx.x * 256 + threadIdx.x;
    if (i >= 64 * 20 * 49) return;
    int oc = i / 980;
    int r  = i % 980;
    int ic = r / 49;
    int ky = (r % 49) / 7;
    int kx = r % 7;
    wt[((ic * 7 + ky) * 7 + kx) * 64 + oc] = w[i];
}

__global__ __launch_bounds__(256) void transpose_wb(const float* __restrict__ w,
                                                    float* __restrict__ wt) {
    int i = blockIdx.x * 256 + threadIdx.x;
    if (i >= 8 * 64 * 64 * 9) return;
    int l  = i / 36864;
    int r  = i % 36864;
    int oc = r / 576;
    int r2 = r % 576;
    int ic = r2 / 9;
    int ky = (r2 % 9) / 3;
    int kx = r2 % 3;
    wt[l * 36864 + ((ic * 3 + ky) * 3 + kx) * 64 + oc] = w[i];
}

// ---------------- conv1 7x7 s2 p3 (20->64) + membrane, split-y tiled --------
// grid (8 = 4 xtiles x 2 yhalves, 8 ocg, 16 n) = 1024 blocks, 256 threads.
// thread (tx 0..15, ty 0..13 active): 8 ocs x 2 output rows.
__global__ __launch_bounds__(256) void conv1_t2(
    const float* __restrict__ x,    // [16,8,20,112,112]
    const float* __restrict__ wt,   // [20][7][7][64]
    float* __restrict__ c_mem,      // [16,64,56,56]
    int t)
{
    __shared__ float tile[C1T];
    const int tid = threadIdx.x;
    const int bx  = blockIdx.x >> 1;     // 0..3 x-tile
    const int yh  = blockIdx.x & 1;      // 0..1 y-half
    const int oc0 = blockIdx.y * 8;
    const int n   = blockIdx.z;
    const int tx  = tid & 15;
    const int ty  = tid >> 4;            // 0..15, active ty<14
    const float* xin = x + ((size_t)(n * 8 + t)) * 20 * 12544;
    const int cbase = 32 * bx - 3;
    const int row0  = 56 * yh - 3;

    float acc[8][2];
#pragma unroll
    for (int o = 0; o < 8; ++o) { acc[o][0] = 0.f; acc[o][1] = 0.f; }

    // stage ic=0
#pragma unroll
    for (int k = 0; k < 9; ++k) {
        int idx = tid + k * 256;
        if (idx < C1T) {
            int r = idx / 37, c = idx - r * 37;
            int ri = row0 + r, ci = cbase + c;
            float v = 0.f;
            if ((unsigned)ri < 112u && (unsigned)ci < 112u) v = xin[ri * 112 + ci];
            tile[idx] = v;
        }
    }

    for (int ic = 0; ic < 20; ++ic) {
        __syncthreads();
        float pre[9];
        if (ic + 1 < 20) {
            const float* src = xin + (ic + 1) * 12544;
#pragma unroll
            for (int k = 0; k < 9; ++k) {
                int idx = tid + k * 256;
                float v = 0.f;
                if (idx < C1T) {
                    int r = idx / 37, c = idx - r * 37;
                    int ri = row0 + r, ci = cbase + c;
                    if ((unsigned)ri < 112u && (unsigned)ci < 112u) v = src[ri * 112 + ci];
                }
                pre[k] = v;
            }
        }
        if (ty < 14) {
            float sub[8][2];
#pragma unroll
            for (int o = 0; o < 8; ++o) { sub[o][0] = 0.f; sub[o][1] = 0.f; }
            const float* wic = wt + ic * (49 * 64) + oc0;
#pragma unroll
            for (int ky = 0; ky < 7; ++ky) {     // ky OUTER (frozen order)
#pragma unroll
                for (int kx = 0; kx < 7; ++kx) { // kx INNER
                    const float* wp = wic + (ky * 7 + kx) * 64;  // uniform -> s_load
                    const float v0 = tile[(4 * ty + 0 + ky) * 37 + 2 * tx + kx];
                    const float v1 = tile[(4 * ty + 2 + ky) * 37 + 2 * tx + kx];
#pragma unroll
                    for (int o = 0; o < 8; ++o) {
                        const float wv = wp[o];
                        sub[o][0] = fmaf(v0, wv, sub[o][0]);
                        sub[o][1] = fmaf(v1, wv, sub[o][1]);
                    }
                }
            }
#pragma unroll
            for (int o = 0; o < 8; ++o) {
                acc[o][0] = acc[o][0] + sub[o][0];
                acc[o][1] = acc[o][1] + sub[o][1];
            }
        }
        __syncthreads();
        if (ic + 1 < 20) {
#pragma unroll
            for (int k = 0; k < 9; ++k) {
                int idx = tid + k * 256;
                if (idx < C1T) tile[idx] = pre[k];
            }
        }
    }

    const int xg = 16 * bx + tx;
    if (ty < 14 && xg < 56) {
#pragma clang fp contract(off)
#pragma unroll
        for (int o = 0; o < 8; ++o) {
#pragma unroll
            for (int d = 0; d < 2; ++d) {
                const int yg = 28 * yh + 2 * ty + d;
                size_t idx = (((size_t)n * 64 + oc0 + o) * 56 + yg) * 56 + xg;
                float m = c_mem[idx] * 0.8f;
                m = m + acc[o][d];
                c_mem[idx] = m;
            }
        }
    }
}

// ---------------- avg_pool 3x3 s2 p1 on spikes(c_mem>0.5), /9 ---------------
__global__ __launch_bounds__(256) void pool1_k(const float* __restrict__ c_mem,
                                               float* __restrict__ cur) {
    int i = blockIdx.x * 256 + threadIdx.x;
    if (i >= NPLANE28) return;
    int xx = i % 28, yy = (i / 28) % 28;
    int p  = i / PLANE28;
    const float* src = c_mem + (size_t)p * 3136;
    float s = 0.f;
    for (int ky = 0; ky < 3; ++ky) {
        int iy = 2 * yy - 1 + ky;
        if ((unsigned)iy >= 56u) continue;
        for (int kx = 0; kx < 3; ++kx) {
            int ix = 2 * xx - 1 + kx;
            if ((unsigned)ix < 56u)
                s += (src[iy * 56 + ix] > 0.5f) ? 1.f : 0.f;
        }
    }
    cur[i] = s / 9.0f;
}

// ---------------- block conv 3x3 s1 p1 (64->64), v3: no LDS, no barriers ----
// grid (4 yq, 8 ocg, 16 n) = 512 blocks; block 256 (196 active, early-exit rest).
// thread = 1 pixel x 8 ocs; 9 masked global taps per ic; SW-pipelined x2.
#define BC_LDV(V, q)                                         \
    {                                                        \
        V[0] = mk0 ? (q)[-29] : 0.f;                         \
        V[1] = mk1 ? (q)[-28] : 0.f;                         \
        V[2] = mk2 ? (q)[-27] : 0.f;                         \
        V[3] = mk3 ? (q)[-1]  : 0.f;                         \
        V[4] =       (q)[0];                                 \
        V[5] = mk5 ? (q)[1]   : 0.f;                         \
        V[6] = mk6 ? (q)[27]  : 0.f;                         \
        V[7] = mk7 ? (q)[28]  : 0.f;                         \
        V[8] = mk8 ? (q)[29]  : 0.f;                         \
    }

#define BC_COMPUTE(V, IC)                                    \
    {                                                        \
        const float* wic = wt + (IC) * 576 + oc0;            \
        float sub[8];                                        \
        _Pragma("unroll")                                    \
        for (int o = 0; o < 8; ++o) sub[o] = 0.f;            \
        _Pragma("unroll")                                    \
        for (int t9 = 0; t9 < 9; ++t9) {   /* ky outer, kx inner (frozen) */ \
            const float* wp = wic + t9 * 64;                 \
            _Pragma("unroll")                                \
            for (int o = 0; o < 8; ++o)                      \
                sub[o] = fmaf(V[t9], wp[o], sub[o]);         \
        }                                                    \
        _Pragma("unroll")                                    \
        for (int o = 0; o < 8; ++o) acc[o] = acc[o] + sub[o];\
    }

template <bool HASRES>
__global__ __launch_bounds__(256) void bconv_v3(
    const float* __restrict__ in,     // [16,64,28,28]
    const float* __restrict__ wt,     // [64ic][3ky][3kx][64oc] (this layer)
    float* __restrict__ mem,
    float* __restrict__ sout,
    const float* __restrict__ resid)
{
    const int tid = threadIdx.x;
    if (tid >= 196) return;           // tail of wave 3 only; no barriers used
    const int yq  = blockIdx.x;       // 0..3
    const int oc0 = blockIdx.y * 8;
    const int n   = blockIdx.z;
    const int xx  = tid % 28;
    const int rl  = tid / 28;         // 0..6
    const int yy  = yq * 7 + rl;

    const bool vy0 = (yy >= 1), vy2 = (yy <= 26);
    const bool vx0 = (xx >= 1), vx2 = (xx <= 26);
    const bool mk0 = vy0 && vx0, mk1 = vy0, mk2 = vy0 && vx2;
    const bool mk3 = vx0,                    mk5 = vx2;
    const bool mk6 = vy2 && vx0, mk7 = vy2, mk8 = vy2 && vx2;

    const float* p = in + (size_t)n * 64 * PLANE28 + yy * 28 + xx;

    float acc[8];
#pragma unroll
    for (int o = 0; o < 8; ++o) acc[o] = 0.f;

    float va[9], vb[9];
    BC_LDV(va, p);
    for (int ic = 0; ic < 64; ic += 2) {
        BC_LDV(vb, p + PLANE28);          // prefetch ic+1 (ic+1 <= 63 always)
        BC_COMPUTE(va, ic);
        if (ic + 2 < 64) BC_LDV(va, p + 2 * PLANE28);  // prefetch ic+2
        BC_COMPUTE(vb, ic + 1);
        p += 2 * PLANE28;
    }

    {
#pragma clang fp contract(off)
#pragma unroll
        for (int o = 0; o < 8; ++o) {
            size_t idx = (((size_t)n * 64 + oc0 + o) * 28 + yy) * 28 + xx;
            float m = mem[idx] * 0.8f;
            m = m + acc[o];
            if (HASRES) m = m + resid[idx];
            mem[idx] = m;
            sout[idx] = (m > 0.5f) ? 1.f : 0.f;
        }
    }
}

// ---------------- feat = avgpool7x7(concat s2 of blocks 0,2,4,6) ------------
__global__ __launch_bounds__(256) void featpool_k(const float* __restrict__ s2all,
                                                  float* __restrict__ feat) {
    int i = blockIdx.x * 256 + threadIdx.x;
    if (i >= 16 * 4096) return;
    int n = i >> 12;
    int f = i & 4095;
    int c = f >> 4;
    int py = (f >> 2) & 3, px = f & 3;
    int s = c >> 6, cc = c & 63;
    const float* src = s2all + ((size_t)(2 * s) * 16 * 64 + n * 64 + cc) * PLANE28;
    float sum = 0.f;
    for (int dy = 0; dy < 7; ++dy)
        for (int dx = 0; dx < 7; ++dx)
            sum += src[(py * 7 + dy) * 28 + px * 7 + dx];
    feat[i] = sum / 49.0f;
}

// ---------------- FC: 8 lanes per (n,cls), frozen 8x512 chains --------------
__global__ __launch_bounds__(256) void fc_w8(
    const float* __restrict__ feat, const float* __restrict__ w,
    const float* __restrict__ b, float* __restrict__ fc_mem,
    float* __restrict__ out) {
    int gt = blockIdx.x * 256 + threadIdx.x;
    int g  = gt >> 3;                 // (n,cls) group
    int j  = gt & 7;                  // chain index
    if (g >= 16 * 101) return;        // 16*101*8 = 12928 = 202 full waves
    int n = g / 101, cls = g % 101;
    const float* fb = feat + (size_t)n * 4096 + j * 512;
    const float* wb = w + (size_t)cls * 4096 + j * 512;
    float sub = 0.f;
    for (int k = 0; k < 512; ++k)
        sub = fmaf(fb[k], wb[k], sub);
    // gather the 8 subtotals and add IN ORDER (frozen chain)
    int lane = threadIdx.x & 63;
    int base = lane & ~7;
    float s0 = __shfl(sub, base + 0, 64);
    float s1 = __shfl(sub, base + 1, 64);
    float s2 = __shfl(sub, base + 2, 64);
    float s3 = __shfl(sub, base + 3, 64);
    float s4 = __shfl(sub, base + 4, 64);
    float s5 = __shfl(sub, base + 5, 64);
    float s6 = __shfl(sub, base + 6, 64);
    float s7 = __shfl(sub, base + 7, 64);
    if (j == 0) {
#pragma clang fp contract(off)
        float a = s0;
        a = a + s1; a = a + s2; a = a + s3;
        a = a + s4; a = a + s5; a = a + s6; a = a + s7;
        float o = a + b[cls];
        float m = fc_mem[g] * 0.8f;
        m = m + o;
        fc_mem[g] = m;
        if (m > 0.5f) out[g] += 0.125f;
    }
}

extern "C" void kernel_launch(void* const* d_in, const int* in_sizes, int n_in,
                              void* d_out, int out_size, void* d_ws, size_t ws_size,
                              hipStream_t stream) {
    const float* x   = (const float*)d_in[0];
    const float* w1  = (const float*)d_in[1];
    const float* wb1 = (const float*)d_in[2];
    const float* wb2 = (const float*)d_in[3];
    const float* fcw = (const float*)d_in[4];
    const float* fcb = (const float*)d_in[5];
    float* out = (float*)d_out;

    // ---- workspace (all fp32): zeroed state first, then scratch
    float* fws    = (float*)d_ws;
    float* c_mem  = fws;                         // 3,211,264
    float* b1m    = c_mem + NPLANE56;            // 8*802,816
    float* b2m    = b1m + 8 * NPLANE28;          // 8*802,816
    float* fc_mem = b2m + 8 * NPLANE28;          // 1,616
    float* cur0   = fc_mem + 1616;               // 802,816
    float* feat   = cur0 + NPLANE28;             // 65,536
    float* s1     = feat + 16 * 4096;            // 802,816
    float* s2all  = s1 + NPLANE28;               // 8*802,816
    float* w1t    = s2all + 8 * NPLANE28;        // 62,720
    float* wb1t   = w1t + 62720;                 // 294,912
    float* wb2t   = wb1t + 294912;               // 294,912

    size_t zeroN = (size_t)NPLANE56 + 16 * NPLANE28 + 1616;
    hipMemsetAsync(c_mem, 0, zeroN * sizeof(float), stream);
    hipMemsetAsync(d_out, 0, 16 * 101 * sizeof(float), stream);

    transpose_w1<<<(62720 + 255) / 256, 256, 0, stream>>>(w1, w1t);
    transpose_wb<<<(294912 + 255) / 256, 256, 0, stream>>>(wb1, wb1t);
    transpose_wb<<<(294912 + 255) / 256, 256, 0, stream>>>(wb2, wb2t);

    for (int t = 0; t < 8; ++t) {
        conv1_t2<<<dim3(8, 8, 16), 256, 0, stream>>>(x, w1t, c_mem, t);
        pool1_k<<<NPLANE28 / 256, 256, 0, stream>>>(c_mem, cur0);
        for (int i = 0; i < 8; ++i) {
            const float* wA = wb1t + (size_t)i * 36864;
            const float* wB = wb2t + (size_t)i * 36864;
            float* m1 = b1m + (size_t)i * NPLANE28;
            float* m2 = b2m + (size_t)i * NPLANE28;
            float* so = s2all + (size_t)i * NPLANE28;
            const float* bin = (i == 0) ? cur0 : s2all + (size_t)(i - 1) * NPLANE28;
            bconv_v3<false><<<dim3(4, 8, 16), 256, 0, stream>>>(bin, wA, m1, s1, nullptr);
            bconv_v3<true><<<dim3(4, 8, 16), 256, 0, stream>>>(s1, wB, m2, so, bin);
        }
        featpool_k<<<16 * 4096 / 256, 256, 0, stream>>>(s2all, feat);
        fc_w8<<<(16 * 101 * 8 + 255) / 256, 256, 0, stream>>>(feat, fcw, fcb, fc_mem, out);
    }
}

// Round 11
// 5167.491 us; speedup vs baseline: 7.6281x; 1.2797x over previous
//
#include <hip/hip_runtime.h>

// ---- geometry ----
#define PLANE28   784                  // 28*28
#define NPLANE28  (16*64*PLANE28)      // 802816  [16,64,28,28]
#define NPLANE56  (16*64*56*56)        // 3211264 [16,64,56,56]
#define C1T_ROWS  61
#define C1T       (C1T_ROWS*37)        // 2257

// FROZEN SEMANTICS (validated rounds 7-10, absmax=0):
//  - conv reductions: per-ic subtotal. sub = fmaf chain over (ky outer, kx inner),
//    OOB as zero-tap fmaf no-op; acc = acc + sub in ic order.
//  - membrane: m = mem*0.8f; m = m + conv; [m = m + resid;]  (contract OFF)
//  - fc: 8 x 512-term sequential fmaf chains, subtotals added in order; o = acc + b.
//  - pool sums are exact small integers (order-free), divided by 9.0f / 49.0f.

// ---------------- weight transposes (once per launch) -----------------------
// conv1_w [64oc][20ic][7ky][7kx] -> w1t [20ic][7ky][7kx][64oc]
__global__ __launch_bounds__(256) void transpose_w1(const float* __restrict__ w,
                                                    float* __restrict__ wt) {
    int i = blockIdx.x * 256 + threadIdx.x;
    if (i >= 64 * 20 * 49) return;
    int oc = i / 980;
    int r  = i % 980;
    int ic = r / 49;
    int ky = (r % 49) / 7;
    int kx = r % 7;
    wt[((ic * 7 + ky) * 7 + kx) * 64 + oc] = w[i];
}

// blocks_w [8][64oc][64ic][3ky][3kx] -> wt [8][16 ocg][64 ic][9 t9][4 oc]
__global__ __launch_bounds__(256) void transpose_wb4(const float* __restrict__ w,
                                                     float* __restrict__ wt) {
    int i = blockIdx.x * 256 + threadIdx.x;
    if (i >= 8 * 64 * 64 * 9) return;
    int l  = i / 36864;
    int r  = i % 36864;
    int oc = r / 576;
    int r2 = r % 576;
    int ic = r2 / 9;
    int t9 = r2 % 9;                  // ky*3+kx (frozen tap order)
    wt[l * 36864 + (oc >> 2) * 2304 + ic * 36 + t9 * 4 + (oc & 3)] = w[i];
}

// ---------------- conv1 7x7 s2 p3 (20->64) + membrane, split-y tiled --------
// (unchanged from round 10 — passed)
__global__ __launch_bounds__(256) void conv1_t2(
    const float* __restrict__ x,    // [16,8,20,112,112]
    const float* __restrict__ wt,   // [20][7][7][64]
    float* __restrict__ c_mem,      // [16,64,56,56]
    int t)
{
    __shared__ float tile[C1T];
    const int tid = threadIdx.x;
    const int bx  = blockIdx.x >> 1;     // 0..3 x-tile
    const int yh  = blockIdx.x & 1;      // 0..1 y-half
    const int oc0 = blockIdx.y * 8;
    const int n   = blockIdx.z;
    const int tx  = tid & 15;
    const int ty  = tid >> 4;            // 0..15, active ty<14
    const float* xin = x + ((size_t)(n * 8 + t)) * 20 * 12544;
    const int cbase = 32 * bx - 3;
    const int row0  = 56 * yh - 3;

    float acc[8][2];
#pragma unroll
    for (int o = 0; o < 8; ++o) { acc[o][0] = 0.f; acc[o][1] = 0.f; }

#pragma unroll
    for (int k = 0; k < 9; ++k) {
        int idx = tid + k * 256;
        if (idx < C1T) {
            int r = idx / 37, c = idx - r * 37;
            int ri = row0 + r, ci = cbase + c;
            float v = 0.f;
            if ((unsigned)ri < 112u && (unsigned)ci < 112u) v = xin[ri * 112 + ci];
            tile[idx] = v;
        }
    }

    for (int ic = 0; ic < 20; ++ic) {
        __syncthreads();
        float pre[9];
        if (ic + 1 < 20) {
            const float* src = xin + (ic + 1) * 12544;
#pragma unroll
            for (int k = 0; k < 9; ++k) {
                int idx = tid + k * 256;
                float v = 0.f;
                if (idx < C1T) {
                    int r = idx / 37, c = idx - r * 37;
                    int ri = row0 + r, ci = cbase + c;
                    if ((unsigned)ri < 112u && (unsigned)ci < 112u) v = src[ri * 112 + ci];
                }
                pre[k] = v;
            }
        }
        if (ty < 14) {
            float sub[8][2];
#pragma unroll
            for (int o = 0; o < 8; ++o) { sub[o][0] = 0.f; sub[o][1] = 0.f; }
            const float* wic = wt + ic * (49 * 64) + oc0;
#pragma unroll
            for (int ky = 0; ky < 7; ++ky) {     // ky OUTER (frozen order)
#pragma unroll
                for (int kx = 0; kx < 7; ++kx) { // kx INNER
                    const float* wp = wic + (ky * 7 + kx) * 64;  // uniform -> s_load
                    const float v0 = tile[(4 * ty + 0 + ky) * 37 + 2 * tx + kx];
                    const float v1 = tile[(4 * ty + 2 + ky) * 37 + 2 * tx + kx];
#pragma unroll
                    for (int o = 0; o < 8; ++o) {
                        const float wv = wp[o];
                        sub[o][0] = fmaf(v0, wv, sub[o][0]);
                        sub[o][1] = fmaf(v1, wv, sub[o][1]);
                    }
                }
            }
#pragma unroll
            for (int o = 0; o < 8; ++o) {
                acc[o][0] = acc[o][0] + sub[o][0];
                acc[o][1] = acc[o][1] + sub[o][1];
            }
        }
        __syncthreads();
        if (ic + 1 < 20) {
#pragma unroll
            for (int k = 0; k < 9; ++k) {
                int idx = tid + k * 256;
                if (idx < C1T) tile[idx] = pre[k];
            }
        }
    }

    const int xg = 16 * bx + tx;
    if (ty < 14 && xg < 56) {
#pragma clang fp contract(off)
#pragma unroll
        for (int o = 0; o < 8; ++o) {
#pragma unroll
            for (int d = 0; d < 2; ++d) {
                const int yg = 28 * yh + 2 * ty + d;
                size_t idx = (((size_t)n * 64 + oc0 + o) * 56 + yg) * 56 + xg;
                float m = c_mem[idx] * 0.8f;
                m = m + acc[o][d];
                c_mem[idx] = m;
            }
        }
    }
}

// ---------------- avg_pool 3x3 s2 p1 on spikes(c_mem>0.5), /9 ---------------
__global__ __launch_bounds__(256) void pool1_k(const float* __restrict__ c_mem,
                                               float* __restrict__ cur) {
    int i = blockIdx.x * 256 + threadIdx.x;
    if (i >= NPLANE28) return;
    int xx = i % 28, yy = (i / 28) % 28;
    int p  = i / PLANE28;
    const float* src = c_mem + (size_t)p * 3136;
    float s = 0.f;
    for (int ky = 0; ky < 3; ++ky) {
        int iy = 2 * yy - 1 + ky;
        if ((unsigned)iy >= 56u) continue;
        for (int kx = 0; kx < 3; ++kx) {
            int ix = 2 * xx - 1 + kx;
            if ((unsigned)ix < 56u)
                s += (src[iy * 56 + ix] > 0.5f) ? 1.f : 0.f;
        }
    }
    cur[i] = s / 9.0f;
}

// ---------------- block conv 3x3 s1 p1 (64->64), v4 -------------------------
// grid (4 yq, 16 ocg, 16 n) = 1024 blocks (4/CU); block 256 (196 active).
// thread = 1 pixel x 4 ocs. Unconditional dwordx3 tap loads + post-mask
// (fmaf(0,w,s)==s, bit-exact). Weights [ocg][ic][t9][4] -> s_load_dwordx4.
#define BC_LD(V, q)                                          \
    {                                                        \
        V[0] = (q)[-29]; V[1] = (q)[-28]; V[2] = (q)[-27];   \
        V[3] = (q)[-1];  V[4] = (q)[0];   V[5] = (q)[1];     \
        V[6] = (q)[27];  V[7] = (q)[28];  V[8] = (q)[29];    \
        V[0] = mk0 ? V[0] : 0.f;                             \
        V[1] = mk1 ? V[1] : 0.f;                             \
        V[2] = mk2 ? V[2] : 0.f;                             \
        V[3] = mk3 ? V[3] : 0.f;                             \
        V[5] = mk5 ? V[5] : 0.f;                             \
        V[6] = mk6 ? V[6] : 0.f;                             \
        V[7] = mk7 ? V[7] : 0.f;                             \
        V[8] = mk8 ? V[8] : 0.f;                             \
    }

#define BC_COMP4(V, IC)                                      \
    {                                                        \
        const float* wic = wblk + (IC) * 36;                 \
        float sub[4];                                        \
        sub[0] = 0.f; sub[1] = 0.f; sub[2] = 0.f; sub[3] = 0.f; \
        _Pragma("unroll")                                    \
        for (int t9 = 0; t9 < 9; ++t9) {   /* ky outer, kx inner (frozen) */ \
            const float* wp = wic + t9 * 4;                  \
            _Pragma("unroll")                                \
            for (int o = 0; o < 4; ++o)                      \
                sub[o] = fmaf(V[t9], wp[o], sub[o]);         \
        }                                                    \
        _Pragma("unroll")                                    \
        for (int o = 0; o < 4; ++o) acc[o] = acc[o] + sub[o];\
    }

template <bool HASRES>
__global__ __launch_bounds__(256, 4) void bconv_v4(
    const float* __restrict__ in,     // [16,64,28,28]
    const float* __restrict__ wt,     // [16 ocg][64 ic][9][4] (this layer)
    float* __restrict__ mem,
    float* __restrict__ sout,
    const float* __restrict__ resid)
{
    const int tid = threadIdx.x;
    if (tid >= 196) return;           // no barriers used; tail waves exit
    const int yq  = blockIdx.x;       // 0..3
    const int ocg = blockIdx.y;       // 0..15
    const int oc0 = ocg * 4;
    const int n   = blockIdx.z;
    const int xx  = tid % 28;
    const int rl  = tid / 28;         // 0..6
    const int yy  = yq * 7 + rl;

    const bool vy0 = (yy >= 1), vy2 = (yy <= 26);
    const bool vx0 = (xx >= 1), vx2 = (xx <= 26);
    const bool mk0 = vy0 && vx0, mk1 = vy0, mk2 = vy0 && vx2;
    const bool mk3 = vx0,                    mk5 = vx2;
    const bool mk6 = vy2 && vx0, mk7 = vy2, mk8 = vy2 && vx2;

    const float* p = in + (size_t)n * 64 * PLANE28 + yy * 28 + xx;
    const float* wblk = wt + ocg * 2304;

    float acc[4];
#pragma unroll
    for (int o = 0; o < 4; ++o) acc[o] = 0.f;

    float va[9], vb[9];
    BC_LD(va, p);
    for (int ic = 0; ic < 64; ic += 2) {
        BC_LD(vb, p + PLANE28);                         // prefetch ic+1
        BC_COMP4(va, ic);
        if (ic + 2 < 64) BC_LD(va, p + 2 * PLANE28);    // prefetch ic+2
        BC_COMP4(vb, ic + 1);
        p += 2 * PLANE28;
    }

    {
#pragma clang fp contract(off)
#pragma unroll
        for (int o = 0; o < 4; ++o) {
            size_t idx = (((size_t)n * 64 + oc0 + o) * 28 + yy) * 28 + xx;
            float m = mem[idx] * 0.8f;
            m = m + acc[o];
            if (HASRES) m = m + resid[idx];
            mem[idx] = m;
            sout[idx] = (m > 0.5f) ? 1.f : 0.f;
        }
    }
}

// ---------------- feat = avgpool7x7(concat s2 of blocks 0,2,4,6) ------------
__global__ __launch_bounds__(256) void featpool_k(const float* __restrict__ s2all,
                                                  float* __restrict__ feat) {
    int i = blockIdx.x * 256 + threadIdx.x;
    if (i >= 16 * 4096) return;
    int n = i >> 12;
    int f = i & 4095;
    int c = f >> 4;
    int py = (f >> 2) & 3, px = f & 3;
    int s = c >> 6, cc = c & 63;
    const float* src = s2all + ((size_t)(2 * s) * 16 * 64 + n * 64 + cc) * PLANE28;
    float sum = 0.f;
    for (int dy = 0; dy < 7; ++dy)
        for (int dx = 0; dx < 7; ++dx)
            sum += src[(py * 7 + dy) * 28 + px * 7 + dx];
    feat[i] = sum / 49.0f;
}

// ---------------- FC: 8 lanes per (n,cls), frozen 8x512 chains --------------
__global__ __launch_bounds__(256) void fc_w8(
    const float* __restrict__ feat, const float* __restrict__ w,
    const float* __restrict__ b, float* __restrict__ fc_mem,
    float* __restrict__ out) {
    int gt = blockIdx.x * 256 + threadIdx.x;
    int g  = gt >> 3;                 // (n,cls) group
    int j  = gt & 7;                  // chain index
    if (g >= 16 * 101) return;
    int n = g / 101, cls = g % 101;
    const float* fb = feat + (size_t)n * 4096 + j * 512;
    const float* wb = w + (size_t)cls * 4096 + j * 512;
    float sub = 0.f;
    for (int k = 0; k < 512; ++k)
        sub = fmaf(fb[k], wb[k], sub);
    int lane = threadIdx.x & 63;
    int base = lane & ~7;
    float s0 = __shfl(sub, base + 0, 64);
    float s1 = __shfl(sub, base + 1, 64);
    float s2 = __shfl(sub, base + 2, 64);
    float s3 = __shfl(sub, base + 3, 64);
    float s4 = __shfl(sub, base + 4, 64);
    float s5 = __shfl(sub, base + 5, 64);
    float s6 = __shfl(sub, base + 6, 64);
    float s7 = __shfl(sub, base + 7, 64);
    if (j == 0) {
#pragma clang fp contract(off)
        float a = s0;
        a = a + s1; a = a + s2; a = a + s3;
        a = a + s4; a = a + s5; a = a + s6; a = a + s7;
        float o = a + b[cls];
        float m = fc_mem[g] * 0.8f;
        m = m + o;
        fc_mem[g] = m;
        if (m > 0.5f) out[g] += 0.125f;
    }
}

extern "C" void kernel_launch(void* const* d_in, const int* in_sizes, int n_in,
                              void* d_out, int out_size, void* d_ws, size_t ws_size,
                              hipStream_t stream) {
    const float* x   = (const float*)d_in[0];
    const float* w1  = (const float*)d_in[1];
    const float* wb1 = (const float*)d_in[2];
    const float* wb2 = (const float*)d_in[3];
    const float* fcw = (const float*)d_in[4];
    const float* fcb = (const float*)d_in[5];
    float* out = (float*)d_out;

    // ---- workspace (all fp32): zeroed state first, then scratch
    float* fws    = (float*)d_ws;
    float* c_mem  = fws;                         // 3,211,264
    float* b1m    = c_mem + NPLANE56;            // 8*802,816
    float* b2m    = b1m + 8 * NPLANE28;          // 8*802,816
    float* fc_mem = b2m + 8 * NPLANE28;          // 1,616
    float* cur0   = fc_mem + 1616;               // 802,816
    float* feat   = cur0 + NPLANE28;             // 65,536
    float* s1     = feat + 16 * 4096;            // 802,816
    float* s2all  = s1 + NPLANE28;               // 8*802,816
    float* w1t    = s2all + 8 * NPLANE28;        // 62,720
    float* wb1t   = w1t + 62720;                 // 294,912
    float* wb2t   = wb1t + 294912;               // 294,912

    size_t zeroN = (size_t)NPLANE56 + 16 * NPLANE28 + 1616;
    hipMemsetAsync(c_mem, 0, zeroN * sizeof(float), stream);
    hipMemsetAsync(d_out, 0, 16 * 101 * sizeof(float), stream);

    transpose_w1<<<(62720 + 255) / 256, 256, 0, stream>>>(w1, w1t);
    transpose_wb4<<<(294912 + 255) / 256, 256, 0, stream>>>(wb1, wb1t);
    transpose_wb4<<<(294912 + 255) / 256, 256, 0, stream>>>(wb2, wb2t);

    for (int t = 0; t < 8; ++t) {
        conv1_t2<<<dim3(8, 8, 16), 256, 0, stream>>>(x, w1t, c_mem, t);
        pool1_k<<<NPLANE28 / 256, 256, 0, stream>>>(c_mem, cur0);
        for (int i = 0; i < 8; ++i) {
            const float* wA = wb1t + (size_t)i * 36864;
            const float* wB = wb2t + (size_t)i * 36864;
            float* m1 = b1m + (size_t)i * NPLANE28;
            float* m2 = b2m + (size_t)i * NPLANE28;
            float* so = s2all + (size_t)i * NPLANE28;
            const float* bin = (i == 0) ? cur0 : s2all + (size_t)(i - 1) * NPLANE28;
            bconv_v4<false><<<dim3(4, 16, 16), 256, 0, stream>>>(bin, wA, m1, s1, nullptr);
            bconv_v4<true><<<dim3(4, 16, 16), 256, 0, stream>>>(s1, wB, m2, so, bin);
        }
        featpool_k<<<16 * 4096 / 256, 256, 0, stream>>>(s2all, feat);
        fc_w8<<<(16 * 101 * 8 + 255) / 256, 256, 0, stream>>>(feat, fcw, fcb, fc_mem, out);
    }
}